// Round 1
// baseline (3549.936 us; speedup 1.0000x reference)
//
#include <hip/hip_runtime.h>
#include <hip/hip_bf16.h>
#include <math.h>

typedef __attribute__((ext_vector_type(8))) __bf16 bf16x8;
typedef __attribute__((ext_vector_type(4))) float f32x4;

#define MFMA16(a, b, c) __builtin_amdgcn_mfma_f32_16x16x32_bf16((a), (b), (c), 0, 0, 0)

// ---------------------------------------------------------------------------
// fp32 -> bf16 cast (4 elems/thread)
// ---------------------------------------------------------------------------
__global__ void cast_bf16_kernel(const float* __restrict__ in, __hip_bfloat16* __restrict__ out) {
    int i = (blockIdx.x * blockDim.x + threadIdx.x) * 4;
    float4 v = *(const float4*)(in + i);
    out[i + 0] = __float2bfloat16(v.x);
    out[i + 1] = __float2bfloat16(v.y);
    out[i + 2] = __float2bfloat16(v.z);
    out[i + 3] = __float2bfloat16(v.w);
}

// ---------------------------------------------------------------------------
// W[K][N] fp32 -> Wt[N][K] bf16 (32x32 LDS tile transpose)
// ---------------------------------------------------------------------------
__global__ void transpose_cast_kernel(const float* __restrict__ w, __hip_bfloat16* __restrict__ wt,
                                      int K, int N) {
    __shared__ float tile[32][33];
    int n0 = blockIdx.x * 32, k0 = blockIdx.y * 32;
    int tx = threadIdx.x;  // 0..31
    int ty = threadIdx.y;  // 0..7
#pragma unroll
    for (int r = 0; r < 4; r++) {
        int k = k0 + ty + r * 8;
        tile[ty + r * 8][tx] = w[(size_t)k * N + n0 + tx];
    }
    __syncthreads();
#pragma unroll
    for (int r = 0; r < 4; r++) {
        int n = n0 + ty + r * 8;
        wt[(size_t)n * K + k0 + tx] = __float2bfloat16(tile[tx][ty + r * 8]);
    }
}

// ---------------------------------------------------------------------------
// Fused QKV projection: C[m][n] = Xb[m][:] . Wt[n][:]
// m = b*2048+s (4096), n in [0,6144): Q | K | V
// Q -> Qraw[b][h][s][d], K -> Kraw[b][kh][s][d], V -> Vt[b][kh][d][s]
// Wave computes 16m x 64n; block = 4 waves along m.
// ---------------------------------------------------------------------------
__global__ __launch_bounds__(256) void gemm_qkv_kernel(
    const __hip_bfloat16* __restrict__ Xb,
    const __hip_bfloat16* __restrict__ Wqt,
    const __hip_bfloat16* __restrict__ Wkt,
    const __hip_bfloat16* __restrict__ Wvt,
    __hip_bfloat16* __restrict__ Qraw,
    __hip_bfloat16* __restrict__ Kraw,
    __hip_bfloat16* __restrict__ Vt) {
    const int K = 4096;
    int wave = threadIdx.x >> 6, lane = threadIdx.x & 63;
    int l15 = lane & 15, quad = lane >> 4;
    int mt = blockIdx.y * 4 + wave;
    const __hip_bfloat16* arow = Xb + (size_t)(mt * 16 + l15) * K + quad * 8;
    int nbase = blockIdx.x * 64;
    const __hip_bfloat16* brow[4];
#pragma unroll
    for (int f = 0; f < 4; f++) {
        int n = nbase + f * 16 + l15;
        const __hip_bfloat16* p;
        if (n < 4096)      p = Wqt + (size_t)n * K;
        else if (n < 5120) p = Wkt + (size_t)(n - 4096) * K;
        else               p = Wvt + (size_t)(n - 5120) * K;
        brow[f] = p + quad * 8;
    }
    f32x4 acc[4];
#pragma unroll
    for (int f = 0; f < 4; f++) acc[f] = (f32x4){0.f, 0.f, 0.f, 0.f};

    for (int k = 0; k < K; k += 32) {
        bf16x8 a = *(const bf16x8*)(arow + k);
#pragma unroll
        for (int f = 0; f < 4; f++) {
            bf16x8 b = *(const bf16x8*)(brow[f] + k);
            acc[f] = MFMA16(a, b, acc[f]);
        }
    }
#pragma unroll
    for (int f = 0; f < 4; f++) {
        int n = nbase + f * 16 + l15;
#pragma unroll
        for (int r = 0; r < 4; r++) {
            int mr = mt * 16 + quad * 4 + r;
            int bb = mr >> 11, s = mr & 2047;
            __hip_bfloat16 hv = __float2bfloat16(acc[f][r]);
            if (n < 4096) {
                int hh = n >> 7, d = n & 127;
                Qraw[(((size_t)(bb * 32 + hh)) * 2048 + s) * 128 + d] = hv;
            } else if (n < 5120) {
                int n2 = n - 4096, hh = n2 >> 7, d = n2 & 127;
                Kraw[(((size_t)(bb * 8 + hh)) * 2048 + s) * 128 + d] = hv;
            } else {
                int n2 = n - 5120, hh = n2 >> 7, d = n2 & 127;
                Vt[(((size_t)(bb * 8 + hh)) * 128 + d) * 2048 + s] = hv;
            }
        }
    }
}

// ---------------------------------------------------------------------------
// In-place RoPE on x[b][h][s][128] bf16. One thread per (b,h,s,d<64) pair.
// ---------------------------------------------------------------------------
__global__ void rope_kernel(__hip_bfloat16* __restrict__ x, const int* __restrict__ pos_ids,
                            int nheads) {
    int idx = blockIdx.x * blockDim.x + threadIdx.x;
    int d = idx & 63;
    int s = (idx >> 6) & 2047;
    int bh = idx >> 17;
    int b = bh / nheads;
    float p = (float)pos_ids[b * 2048 + s];
    // inv_freq = THETA^(-d/64) = exp(-d * ln(1e6)/64)
    float inv = expf(-(float)d * 0.2158673552f);
    float ang = p * inv;
    float sn = sinf(ang), cs = cosf(ang);
    size_t base = ((size_t)bh * 2048 + s) * 128;
    float x1 = __bfloat162float(x[base + d]);
    float x2 = __bfloat162float(x[base + d + 64]);
    x[base + d]      = __float2bfloat16(x1 * cs - x2 * sn);
    x[base + d + 64] = __float2bfloat16(x2 * cs + x1 * sn);
}

// ---------------------------------------------------------------------------
// Flash attention, sliding window 1024, GQA rep=4.
// One wave per (qtile of 16 rows, h, b). Key tiles of 32.
// Qb[b][h][s][d], Kb[b][kh][s][d], Vt[b][kh][d][s] -> AO[b][s][h*128+d]
// ---------------------------------------------------------------------------
__global__ __launch_bounds__(64) void attn_kernel(
    const __hip_bfloat16* __restrict__ Qb, const __hip_bfloat16* __restrict__ Kb,
    const __hip_bfloat16* __restrict__ Vt, __hip_bfloat16* __restrict__ AO) {
    const int S = 2048, D = 128;
    int lane = threadIdx.x;
    int l15 = lane & 15, quad = lane >> 4;
    int qt = blockIdx.x, h = blockIdx.y, b = blockIdx.z;
    int i0 = qt * 16;
    int kh = h >> 2;
    const __hip_bfloat16* Qh = Qb + (size_t)(b * 32 + h) * S * D;
    const __hip_bfloat16* Kh = Kb + (size_t)(b * 8 + kh) * S * D;
    const __hip_bfloat16* Vh = Vt + (size_t)(b * 8 + kh) * D * S;

    bf16x8 qf[4];
    {
        const __hip_bfloat16* qrow = Qh + (size_t)(i0 + l15) * D + quad * 8;
#pragma unroll
        for (int kk = 0; kk < 4; kk++) qf[kk] = *(const bf16x8*)(qrow + kk * 32);
    }
    f32x4 o[8];
#pragma unroll
    for (int f = 0; f < 8; f++) o[f] = (f32x4){0.f, 0.f, 0.f, 0.f};
    float mrow[4] = {-1e30f, -1e30f, -1e30f, -1e30f};
    float lrow[4] = {0.f, 0.f, 0.f, 0.f};
    __shared__ __hip_bfloat16 Plds[16][32];
    int kstart = (i0 > 1023) ? ((i0 - 1023) & ~31) : 0;
    const float scale = 0.08838834764831845f;  // 1/sqrt(128)

    for (int key0 = kstart; key0 <= i0 + 15; key0 += 32) {
        f32x4 sc0 = (f32x4){0.f, 0.f, 0.f, 0.f};
        f32x4 sc1 = (f32x4){0.f, 0.f, 0.f, 0.f};
        {
            const __hip_bfloat16* kr0 = Kh + (size_t)(key0 + l15) * D + quad * 8;
            const __hip_bfloat16* kr1 = kr0 + 16 * D;
#pragma unroll
            for (int kk = 0; kk < 4; kk++) {
                sc0 = MFMA16(qf[kk], *(const bf16x8*)(kr0 + kk * 32), sc0);
                sc1 = MFMA16(qf[kk], *(const bf16x8*)(kr1 + kk * 32), sc1);
            }
        }
#pragma unroll
        for (int r = 0; r < 4; r++) {
            int i = i0 + quad * 4 + r;
            int j0 = key0 + l15, j1 = j0 + 16;
            float v0 = (j0 <= i && i - j0 < 1024) ? sc0[r] * scale : -1e30f;
            float v1 = (j1 <= i && i - j1 < 1024) ? sc1[r] * scale : -1e30f;
            float mx = fmaxf(v0, v1);
#pragma unroll
            for (int msk = 1; msk < 16; msk <<= 1) mx = fmaxf(mx, __shfl_xor(mx, msk, 64));
            float mnew = fmaxf(mrow[r], mx);
            float alpha = expf(mrow[r] - mnew);
            float p0 = expf(v0 - mnew);
            float p1 = expf(v1 - mnew);
            mrow[r] = mnew;
            float rs = p0 + p1;
#pragma unroll
            for (int msk = 1; msk < 16; msk <<= 1) rs += __shfl_xor(rs, msk, 64);
            lrow[r] = lrow[r] * alpha + rs;
#pragma unroll
            for (int f = 0; f < 8; f++) o[f][r] *= alpha;
            Plds[quad * 4 + r][l15] = __float2bfloat16(p0);
            Plds[quad * 4 + r][16 + l15] = __float2bfloat16(p1);
        }
        __syncthreads();
        bf16x8 pf = *(const bf16x8*)(&Plds[l15][quad * 8]);
        int sb = key0 + quad * 8;
#pragma unroll
        for (int f = 0; f < 8; f++) {
            bf16x8 vf = *(const bf16x8*)(Vh + (size_t)(f * 16 + l15) * S + sb);
            o[f] = MFMA16(pf, vf, o[f]);
        }
        __syncthreads();
    }
#pragma unroll
    for (int r = 0; r < 4; r++) {
        int srow = i0 + quad * 4 + r;
        float invl = 1.f / lrow[r];
        __hip_bfloat16* orow = AO + ((size_t)(b * 2048 + srow) * 4096) + h * 128;
#pragma unroll
        for (int f = 0; f < 8; f++) orow[f * 16 + l15] = __float2bfloat16(o[f][r] * invl);
    }
}

// ---------------------------------------------------------------------------
// Output projection: out[m][n] = AO[m][:] . Wot[n][:], fp32 out.
// ---------------------------------------------------------------------------
__global__ __launch_bounds__(256) void gemm_out_kernel(
    const __hip_bfloat16* __restrict__ A, const __hip_bfloat16* __restrict__ Bt,
    float* __restrict__ C) {
    const int K = 4096, N = 4096;
    int wave = threadIdx.x >> 6, lane = threadIdx.x & 63;
    int l15 = lane & 15, quad = lane >> 4;
    int mt = blockIdx.y * 4 + wave;
    const __hip_bfloat16* arow = A + (size_t)(mt * 16 + l15) * K + quad * 8;
    int nbase = blockIdx.x * 64;
    const __hip_bfloat16* brow[4];
#pragma unroll
    for (int f = 0; f < 4; f++) brow[f] = Bt + (size_t)(nbase + f * 16 + l15) * K + quad * 8;
    f32x4 acc[4];
#pragma unroll
    for (int f = 0; f < 4; f++) acc[f] = (f32x4){0.f, 0.f, 0.f, 0.f};

    for (int k = 0; k < K; k += 32) {
        bf16x8 a = *(const bf16x8*)(arow + k);
#pragma unroll
        for (int f = 0; f < 4; f++) {
            bf16x8 b = *(const bf16x8*)(brow[f] + k);
            acc[f] = MFMA16(a, b, acc[f]);
        }
    }
#pragma unroll
    for (int f = 0; f < 4; f++) {
#pragma unroll
        for (int r = 0; r < 4; r++) {
            int mr = mt * 16 + quad * 4 + r;
            C[(size_t)mr * N + nbase + f * 16 + l15] = acc[f][r];
        }
    }
}

// ---------------------------------------------------------------------------
extern "C" void kernel_launch(void* const* d_in, const int* in_sizes, int n_in,
                              void* d_out, int out_size, void* d_ws, size_t ws_size,
                              hipStream_t stream) {
    (void)in_sizes; (void)n_in; (void)out_size;
    const float* hidden = (const float*)d_in[0];
    const int* pos = (const int*)d_in[1];
    const float* wq = (const float*)d_in[2];
    const float* wk = (const float*)d_in[3];
    const float* wv = (const float*)d_in[4];
    const float* wo = (const float*)d_in[5];
    float* out = (float*)d_out;

    const int M = 4096;  // B*S
    char* ws = (char*)d_ws;
    size_t off = 0;
    auto alloc = [&](size_t bytes) { char* p = ws + off; off += bytes; return p; };
    __hip_bfloat16* Xb  = (__hip_bfloat16*)alloc((size_t)M * 4096 * 2);
    __hip_bfloat16* Wqt = (__hip_bfloat16*)alloc((size_t)4096 * 4096 * 2);
    __hip_bfloat16* Wkt = (__hip_bfloat16*)alloc((size_t)1024 * 4096 * 2);
    __hip_bfloat16* Wvt = (__hip_bfloat16*)alloc((size_t)1024 * 4096 * 2);
    __hip_bfloat16* Wot = (__hip_bfloat16*)alloc((size_t)4096 * 4096 * 2);
    __hip_bfloat16* Qb  = (__hip_bfloat16*)alloc((size_t)M * 4096 * 2);
    __hip_bfloat16* Kb  = (__hip_bfloat16*)alloc((size_t)M * 1024 * 2);
    __hip_bfloat16* Vt  = (__hip_bfloat16*)alloc((size_t)M * 1024 * 2);
    __hip_bfloat16* AO  = (__hip_bfloat16*)alloc((size_t)M * 4096 * 2);
    if (off > ws_size) return;  // workspace too small: fail loudly via wrong output

    cast_bf16_kernel<<<(M * 4096) / 1024, 256, 0, stream>>>(hidden, Xb);
    dim3 tb(32, 8);
    transpose_cast_kernel<<<dim3(128, 128), tb, 0, stream>>>(wq, Wqt, 4096, 4096);
    transpose_cast_kernel<<<dim3(32, 128),  tb, 0, stream>>>(wk, Wkt, 4096, 1024);
    transpose_cast_kernel<<<dim3(32, 128),  tb, 0, stream>>>(wv, Wvt, 4096, 1024);
    transpose_cast_kernel<<<dim3(128, 128), tb, 0, stream>>>(wo, Wot, 4096, 4096);

    gemm_qkv_kernel<<<dim3(96, 64), 256, 0, stream>>>(Xb, Wqt, Wkt, Wvt, Qb, Kb, Vt);

    rope_kernel<<<(2 * 32 * 2048 * 64) / 256, 256, 0, stream>>>(Qb, pos, 32);
    rope_kernel<<<(2 * 8 * 2048 * 64) / 256, 256, 0, stream>>>(Kb, pos, 8);

    attn_kernel<<<dim3(128, 32, 2), 64, 0, stream>>>(Qb, Kb, Vt, AO);

    gemm_out_kernel<<<dim3(64, 64), 256, 0, stream>>>(AO, Wot, out);
}

// Round 2
// 1167.822 us; speedup vs baseline: 3.0398x; 3.0398x over previous
//
#include <hip/hip_runtime.h>
#include <hip/hip_bf16.h>
#include <math.h>

typedef __attribute__((ext_vector_type(8))) __bf16 bf16x8;
typedef __attribute__((ext_vector_type(4))) float f32x4;

#define MFMA16(a, b, c) __builtin_amdgcn_mfma_f32_16x16x32_bf16((a), (b), (c), 0, 0, 0)

__device__ inline void gld_lds16(const __hip_bfloat16* g, __hip_bfloat16* l) {
    __builtin_amdgcn_global_load_lds(
        (const __attribute__((address_space(1))) void*)g,
        (__attribute__((address_space(3))) void*)l, 16, 0, 0);
}

// ---------------------------------------------------------------------------
// fp32 -> bf16 cast (4 elems/thread)
// ---------------------------------------------------------------------------
__global__ void cast_bf16_kernel(const float* __restrict__ in, __hip_bfloat16* __restrict__ out) {
    int i = (blockIdx.x * blockDim.x + threadIdx.x) * 4;
    float4 v = *(const float4*)(in + i);
    out[i + 0] = __float2bfloat16(v.x);
    out[i + 1] = __float2bfloat16(v.y);
    out[i + 2] = __float2bfloat16(v.z);
    out[i + 3] = __float2bfloat16(v.w);
}

// ---------------------------------------------------------------------------
// W[K][N] fp32 -> Wt[N][K] bf16 (32x32 LDS tile transpose)
// ---------------------------------------------------------------------------
__global__ void transpose_cast_kernel(const float* __restrict__ w, __hip_bfloat16* __restrict__ wt,
                                      int K, int N) {
    __shared__ float tile[32][33];
    int n0 = blockIdx.x * 32, k0 = blockIdx.y * 32;
    int tx = threadIdx.x;  // 0..31
    int ty = threadIdx.y;  // 0..7
#pragma unroll
    for (int r = 0; r < 4; r++) {
        int k = k0 + ty + r * 8;
        tile[ty + r * 8][tx] = w[(size_t)k * N + n0 + tx];
    }
    __syncthreads();
#pragma unroll
    for (int r = 0; r < 4; r++) {
        int n = n0 + ty + r * 8;
        wt[(size_t)n * K + k0 + tx] = __float2bfloat16(tile[tx][ty + r * 8]);
    }
}

// ---------------------------------------------------------------------------
// Tiled QKV GEMM (m97 structure): C[m][n] = Xb[m][:] . Wt[n][:]
// M=4096 (b*2048+s), N=6144 (Q|K|V concat), K=4096.
// 128x128 tile, BK=32, 4 waves (2x2), LDS staging via global_load_lds w=16.
// Epilogue scatters: Q->Qraw[b][h][s][d], K->Kraw[b][kh][s][d], V->Vt[b][kh][d][s]
// ---------------------------------------------------------------------------
__global__ __launch_bounds__(256) void gemm_qkv_kernel(
    const __hip_bfloat16* __restrict__ Xb,
    const __hip_bfloat16* __restrict__ Wt,   // [6144][4096]
    __hip_bfloat16* __restrict__ Qraw,
    __hip_bfloat16* __restrict__ Kraw,
    __hip_bfloat16* __restrict__ Vt) {
    const int K = 4096;
    __shared__ __hip_bfloat16 As[128 * 32];
    __shared__ __hip_bfloat16 Bs[128 * 32];

    int tid = threadIdx.x;
    int wave = tid >> 6, lane = tid & 63;
    int l15 = lane & 15, quad = lane >> 4;
    int m0 = blockIdx.y * 128, n0 = blockIdx.x * 128;

    // staging addresses: wave w stages tile rows [w*32, w*32+32)
    int srow = wave * 32 + (lane >> 2);
    int scol = (lane & 3) * 8;
    const __hip_bfloat16* agp0 = Xb + (size_t)(m0 + srow) * K + scol;
    const __hip_bfloat16* agp1 = agp0 + (size_t)16 * K;
    const __hip_bfloat16* bgp0 = Wt + (size_t)(n0 + srow) * K + scol;
    const __hip_bfloat16* bgp1 = bgp0 + (size_t)16 * K;
    __hip_bfloat16* asl0 = As + wave * 1024;
    __hip_bfloat16* asl1 = asl0 + 512;
    __hip_bfloat16* bsl0 = Bs + wave * 1024;
    __hip_bfloat16* bsl1 = bsl0 + 512;

    int wm = wave & 1, wn = wave >> 1;
    const __hip_bfloat16* afr = As + (size_t)(wm * 64 + l15) * 32 + quad * 8;
    const __hip_bfloat16* bfr = Bs + (size_t)(wn * 64 + l15) * 32 + quad * 8;

    f32x4 acc[4][4];
#pragma unroll
    for (int mi = 0; mi < 4; mi++)
#pragma unroll
        for (int ni = 0; ni < 4; ni++) acc[mi][ni] = (f32x4){0.f, 0.f, 0.f, 0.f};

    for (int k0 = 0; k0 < K; k0 += 32) {
        gld_lds16(agp0 + k0, asl0);
        gld_lds16(agp1 + k0, asl1);
        gld_lds16(bgp0 + k0, bsl0);
        gld_lds16(bgp1 + k0, bsl1);
        __syncthreads();
        bf16x8 a[4], b[4];
#pragma unroll
        for (int mi = 0; mi < 4; mi++) a[mi] = *(const bf16x8*)(afr + mi * 16 * 32);
#pragma unroll
        for (int ni = 0; ni < 4; ni++) b[ni] = *(const bf16x8*)(bfr + ni * 16 * 32);
#pragma unroll
        for (int mi = 0; mi < 4; mi++)
#pragma unroll
            for (int ni = 0; ni < 4; ni++) acc[mi][ni] = MFMA16(a[mi], b[ni], acc[mi][ni]);
        __syncthreads();
    }

#pragma unroll
    for (int mi = 0; mi < 4; mi++) {
#pragma unroll
        for (int ni = 0; ni < 4; ni++) {
            int n = n0 + wn * 64 + ni * 16 + l15;
#pragma unroll
            for (int r = 0; r < 4; r++) {
                int m = m0 + wm * 64 + mi * 16 + quad * 4 + r;
                int bb = m >> 11, s = m & 2047;
                __hip_bfloat16 hv = __float2bfloat16(acc[mi][ni][r]);
                if (n < 4096) {
                    int hh = n >> 7, d = n & 127;
                    Qraw[(((size_t)(bb * 32 + hh)) * 2048 + s) * 128 + d] = hv;
                } else if (n < 5120) {
                    int n2 = n - 4096, hh = n2 >> 7, d = n2 & 127;
                    Kraw[(((size_t)(bb * 8 + hh)) * 2048 + s) * 128 + d] = hv;
                } else {
                    int n2 = n - 5120, hh = n2 >> 7, d = n2 & 127;
                    Vt[(((size_t)(bb * 8 + hh)) * 128 + d) * 2048 + s] = hv;
                }
            }
        }
    }
}

// ---------------------------------------------------------------------------
// Tiled output GEMM: out[m][n] = AO[m][:] . Wot[n][:], fp32 out. M=N=K=4096.
// ---------------------------------------------------------------------------
__global__ __launch_bounds__(256) void gemm_out_kernel(
    const __hip_bfloat16* __restrict__ A, const __hip_bfloat16* __restrict__ Bt,
    float* __restrict__ C) {
    const int K = 4096, N = 4096;
    __shared__ __hip_bfloat16 As[128 * 32];
    __shared__ __hip_bfloat16 Bs[128 * 32];

    int tid = threadIdx.x;
    int wave = tid >> 6, lane = tid & 63;
    int l15 = lane & 15, quad = lane >> 4;
    int m0 = blockIdx.y * 128, n0 = blockIdx.x * 128;

    int srow = wave * 32 + (lane >> 2);
    int scol = (lane & 3) * 8;
    const __hip_bfloat16* agp0 = A + (size_t)(m0 + srow) * K + scol;
    const __hip_bfloat16* agp1 = agp0 + (size_t)16 * K;
    const __hip_bfloat16* bgp0 = Bt + (size_t)(n0 + srow) * K + scol;
    const __hip_bfloat16* bgp1 = bgp0 + (size_t)16 * K;
    __hip_bfloat16* asl0 = As + wave * 1024;
    __hip_bfloat16* asl1 = asl0 + 512;
    __hip_bfloat16* bsl0 = Bs + wave * 1024;
    __hip_bfloat16* bsl1 = bsl0 + 512;

    int wm = wave & 1, wn = wave >> 1;
    const __hip_bfloat16* afr = As + (size_t)(wm * 64 + l15) * 32 + quad * 8;
    const __hip_bfloat16* bfr = Bs + (size_t)(wn * 64 + l15) * 32 + quad * 8;

    f32x4 acc[4][4];
#pragma unroll
    for (int mi = 0; mi < 4; mi++)
#pragma unroll
        for (int ni = 0; ni < 4; ni++) acc[mi][ni] = (f32x4){0.f, 0.f, 0.f, 0.f};

    for (int k0 = 0; k0 < K; k0 += 32) {
        gld_lds16(agp0 + k0, asl0);
        gld_lds16(agp1 + k0, asl1);
        gld_lds16(bgp0 + k0, bsl0);
        gld_lds16(bgp1 + k0, bsl1);
        __syncthreads();
        bf16x8 a[4], b[4];
#pragma unroll
        for (int mi = 0; mi < 4; mi++) a[mi] = *(const bf16x8*)(afr + mi * 16 * 32);
#pragma unroll
        for (int ni = 0; ni < 4; ni++) b[ni] = *(const bf16x8*)(bfr + ni * 16 * 32);
#pragma unroll
        for (int mi = 0; mi < 4; mi++)
#pragma unroll
            for (int ni = 0; ni < 4; ni++) acc[mi][ni] = MFMA16(a[mi], b[ni], acc[mi][ni]);
        __syncthreads();
    }

#pragma unroll
    for (int mi = 0; mi < 4; mi++) {
#pragma unroll
        for (int ni = 0; ni < 4; ni++) {
            int n = n0 + wn * 64 + ni * 16 + l15;
#pragma unroll
            for (int r = 0; r < 4; r++) {
                int m = m0 + wm * 64 + mi * 16 + quad * 4 + r;
                C[(size_t)m * N + n] = acc[mi][ni][r];
            }
        }
    }
}

// ---------------------------------------------------------------------------
// In-place RoPE on x[b][h][s][128] bf16. One thread per (b,h,s,d<64) pair.
// ---------------------------------------------------------------------------
__global__ void rope_kernel(__hip_bfloat16* __restrict__ x, const int* __restrict__ pos_ids,
                            int nheads) {
    int idx = blockIdx.x * blockDim.x + threadIdx.x;
    int d = idx & 63;
    int s = (idx >> 6) & 2047;
    int bh = idx >> 17;
    int b = bh / nheads;
    float p = (float)pos_ids[b * 2048 + s];
    float inv = expf(-(float)d * 0.2158673552f);  // THETA^(-d/64)
    float ang = p * inv;
    float sn = sinf(ang), cs = cosf(ang);
    size_t base = ((size_t)bh * 2048 + s) * 128;
    float x1 = __bfloat162float(x[base + d]);
    float x2 = __bfloat162float(x[base + d + 64]);
    x[base + d]      = __float2bfloat16(x1 * cs - x2 * sn);
    x[base + d + 64] = __float2bfloat16(x2 * cs + x1 * sn);
}

// ---------------------------------------------------------------------------
// Flash attention, sliding window 1024, GQA rep=4.
// One wave per (qtile of 16 rows, h, b). Key tiles of 32.
// ---------------------------------------------------------------------------
__global__ __launch_bounds__(64) void attn_kernel(
    const __hip_bfloat16* __restrict__ Qb, const __hip_bfloat16* __restrict__ Kb,
    const __hip_bfloat16* __restrict__ Vt, __hip_bfloat16* __restrict__ AO) {
    const int S = 2048, D = 128;
    int lane = threadIdx.x;
    int l15 = lane & 15, quad = lane >> 4;
    int qt = blockIdx.x, h = blockIdx.y, b = blockIdx.z;
    int i0 = qt * 16;
    int kh = h >> 2;
    const __hip_bfloat16* Qh = Qb + (size_t)(b * 32 + h) * S * D;
    const __hip_bfloat16* Kh = Kb + (size_t)(b * 8 + kh) * S * D;
    const __hip_bfloat16* Vh = Vt + (size_t)(b * 8 + kh) * D * S;

    bf16x8 qf[4];
    {
        const __hip_bfloat16* qrow = Qh + (size_t)(i0 + l15) * D + quad * 8;
#pragma unroll
        for (int kk = 0; kk < 4; kk++) qf[kk] = *(const bf16x8*)(qrow + kk * 32);
    }
    f32x4 o[8];
#pragma unroll
    for (int f = 0; f < 8; f++) o[f] = (f32x4){0.f, 0.f, 0.f, 0.f};
    float mrow[4] = {-1e30f, -1e30f, -1e30f, -1e30f};
    float lrow[4] = {0.f, 0.f, 0.f, 0.f};
    __shared__ __hip_bfloat16 Plds[16][32];
    int kstart = (i0 > 1023) ? ((i0 - 1023) & ~31) : 0;
    const float scale = 0.08838834764831845f;  // 1/sqrt(128)

    for (int key0 = kstart; key0 <= i0 + 15; key0 += 32) {
        f32x4 sc0 = (f32x4){0.f, 0.f, 0.f, 0.f};
        f32x4 sc1 = (f32x4){0.f, 0.f, 0.f, 0.f};
        {
            const __hip_bfloat16* kr0 = Kh + (size_t)(key0 + l15) * D + quad * 8;
            const __hip_bfloat16* kr1 = kr0 + 16 * D;
#pragma unroll
            for (int kk = 0; kk < 4; kk++) {
                sc0 = MFMA16(qf[kk], *(const bf16x8*)(kr0 + kk * 32), sc0);
                sc1 = MFMA16(qf[kk], *(const bf16x8*)(kr1 + kk * 32), sc1);
            }
        }
#pragma unroll
        for (int r = 0; r < 4; r++) {
            int i = i0 + quad * 4 + r;
            int j0 = key0 + l15, j1 = j0 + 16;
            float v0 = (j0 <= i && i - j0 < 1024) ? sc0[r] * scale : -1e30f;
            float v1 = (j1 <= i && i - j1 < 1024) ? sc1[r] * scale : -1e30f;
            float mx = fmaxf(v0, v1);
#pragma unroll
            for (int msk = 1; msk < 16; msk <<= 1) mx = fmaxf(mx, __shfl_xor(mx, msk, 64));
            float mnew = fmaxf(mrow[r], mx);
            float alpha = expf(mrow[r] - mnew);
            float p0 = expf(v0 - mnew);
            float p1 = expf(v1 - mnew);
            mrow[r] = mnew;
            float rs = p0 + p1;
#pragma unroll
            for (int msk = 1; msk < 16; msk <<= 1) rs += __shfl_xor(rs, msk, 64);
            lrow[r] = lrow[r] * alpha + rs;
#pragma unroll
            for (int f = 0; f < 8; f++) o[f][r] *= alpha;
            Plds[quad * 4 + r][l15] = __float2bfloat16(p0);
            Plds[quad * 4 + r][16 + l15] = __float2bfloat16(p1);
        }
        __syncthreads();
        bf16x8 pf = *(const bf16x8*)(&Plds[l15][quad * 8]);
        int sb = key0 + quad * 8;
#pragma unroll
        for (int f = 0; f < 8; f++) {
            bf16x8 vf = *(const bf16x8*)(Vh + (size_t)(f * 16 + l15) * S + sb);
            o[f] = MFMA16(pf, vf, o[f]);
        }
        __syncthreads();
    }
#pragma unroll
    for (int r = 0; r < 4; r++) {
        int srow = i0 + quad * 4 + r;
        float invl = 1.f / lrow[r];
        __hip_bfloat16* orow = AO + ((size_t)(b * 2048 + srow) * 4096) + h * 128;
#pragma unroll
        for (int f = 0; f < 8; f++) orow[f * 16 + l15] = __float2bfloat16(o[f][r] * invl);
    }
}

// ---------------------------------------------------------------------------
extern "C" void kernel_launch(void* const* d_in, const int* in_sizes, int n_in,
                              void* d_out, int out_size, void* d_ws, size_t ws_size,
                              hipStream_t stream) {
    (void)in_sizes; (void)n_in; (void)out_size;
    const float* hidden = (const float*)d_in[0];
    const int* pos = (const int*)d_in[1];
    const float* wq = (const float*)d_in[2];
    const float* wk = (const float*)d_in[3];
    const float* wv = (const float*)d_in[4];
    const float* wo = (const float*)d_in[5];
    float* out = (float*)d_out;

    const int M = 4096;  // B*S
    char* ws = (char*)d_ws;
    size_t off = 0;
    auto alloc = [&](size_t bytes) { char* p = ws + off; off += bytes; return p; };
    __hip_bfloat16* Xb    = (__hip_bfloat16*)alloc((size_t)M * 4096 * 2);
    __hip_bfloat16* Wqkvt = (__hip_bfloat16*)alloc((size_t)6144 * 4096 * 2);
    __hip_bfloat16* Wot   = (__hip_bfloat16*)alloc((size_t)4096 * 4096 * 2);
    __hip_bfloat16* Qb    = (__hip_bfloat16*)alloc((size_t)M * 4096 * 2);
    __hip_bfloat16* Kb    = (__hip_bfloat16*)alloc((size_t)M * 1024 * 2);
    __hip_bfloat16* Vt    = (__hip_bfloat16*)alloc((size_t)M * 1024 * 2);
    __hip_bfloat16* AO    = (__hip_bfloat16*)alloc((size_t)M * 4096 * 2);
    if (off > ws_size) return;

    cast_bf16_kernel<<<(M * 4096) / 1024, 256, 0, stream>>>(hidden, Xb);
    dim3 tb(32, 8);
    transpose_cast_kernel<<<dim3(128, 128), tb, 0, stream>>>(wq, Wqkvt, 4096, 4096);
    transpose_cast_kernel<<<dim3(32, 128),  tb, 0, stream>>>(wk, Wqkvt + (size_t)4096 * 4096, 4096, 1024);
    transpose_cast_kernel<<<dim3(32, 128),  tb, 0, stream>>>(wv, Wqkvt + (size_t)5120 * 4096, 4096, 1024);
    transpose_cast_kernel<<<dim3(128, 128), tb, 0, stream>>>(wo, Wot, 4096, 4096);

    gemm_qkv_kernel<<<dim3(48, 32), 256, 0, stream>>>(Xb, Wqkvt, Qb, Kb, Vt);

    rope_kernel<<<(2 * 32 * 2048 * 64) / 256, 256, 0, stream>>>(Qb, pos, 32);
    rope_kernel<<<(2 * 8 * 2048 * 64) / 256, 256, 0, stream>>>(Kb, pos, 8);

    attn_kernel<<<dim3(128, 32, 2), 64, 0, stream>>>(Qb, Kb, Vt, AO);

    gemm_out_kernel<<<dim3(32, 32), 256, 0, stream>>>(AO, Wot, out);
}